// Round 2
// baseline (126.979 us; speedup 1.0000x reference)
//
#include <hip/hip_runtime.h>
#include <math.h>
#include <stdint.h>

#define NB 64
#define NL 3168
#define NC 64
#define ND 512
#define NK 16
#define NW 198
#define NM 12672   // NB*NW rows
#define KD 1024    // NC*NK contraction dim, flattened as k*64+c

typedef __attribute__((ext_vector_type(8))) short bf8_t;   // 8 bf16 (4 VGPR) MFMA A/B frag
typedef __attribute__((ext_vector_type(4))) float f4_t;    // MFMA C/D frag

typedef const unsigned int __attribute__((address_space(1)))* as1_u32p;
typedef unsigned int __attribute__((address_space(3)))* as3_u32p;

__device__ __forceinline__ void gl_lds16(const void* g, void* l) {
  // global -> LDS direct DMA, 16B per lane. LDS dest = wave-uniform base + lane*16.
  __builtin_amdgcn_global_load_lds((as1_u32p)(uintptr_t)g,
                                   (as3_u32p)(unsigned int)(uintptr_t)l, 16, 0, 0);
}

__device__ __forceinline__ unsigned short f2bf(float f) {
  union { float f; unsigned u; } v; v.f = f;
  unsigned r = v.u + 0x7FFFu + ((v.u >> 16) & 1u);
  return (unsigned short)(r >> 16);
}

// ---------------------------------------------------------------------------
// prep: wdeft[d][k*64+c] = w_def[d][c][k] (bf16); wofft[o][k*64+c] = w_off[o][c][k];
//       pe[pos][d] table (f32); cls rows of output
// ---------------------------------------------------------------------------
__global__ void prep_kernel(const float* __restrict__ w_off, const float* __restrict__ w_def,
                            const float* __restrict__ cls, unsigned short* __restrict__ wofft,
                            unsigned short* __restrict__ wdeft, float* __restrict__ pe,
                            float* __restrict__ out) {
  int id = blockIdx.x * 256 + threadIdx.x;
  if (id < 524288) {
    int d = id >> 10, kc = id & 1023, k = kc >> 6, c = kc & 63;
    wdeft[id] = f2bf(w_def[d * 1024 + c * 16 + k]);
    return;
  }
  id -= 524288;
  if (id < 32768) {
    int o = id >> 10, kc = id & 1023, k = kc >> 6, c = kc & 63;
    wofft[id] = f2bf(w_off[o * 1024 + c * 16 + k]);
    return;
  }
  id -= 32768;
  if (id < 101888) {   // 199 * 512 positional-encoding table
    int pos = id >> 9, d = id & 511;
    int i = d >> 1;
    float freq = expf((float)(2 * i) * (-9.210340371976184f / 512.0f));
    float arg = (float)pos * freq;
    pe[id] = (d & 1) ? cosf(arg) : sinf(arg);
    return;
  }
  id -= 101888;
  {  // 64 * 512 cls-token rows: out[b][0][d] = cls[d] + pe[0][d]
    int b = id >> 9, d = id & 511;
    out[(size_t)(b * 199) * 512 + d] = cls[d] + ((d & 1) ? 1.0f : 0.0f);
  }
}

// ---------------------------------------------------------------------------
// fused offset-GEMM + sampling: one wave per 16 rows (792 blocks x 64 thr).
// Phase 1: off[16 rows][32] = x-rows @ wofft^T + b_off   (MFMA, A from global)
// Phase 2: sample the same 16 rows -> val_ws (bf16)
// ---------------------------------------------------------------------------
__launch_bounds__(64)
__global__ void offsample_kernel(const float* __restrict__ x,
                                 const unsigned short* __restrict__ wofft,
                                 const float* __restrict__ b_off,
                                 unsigned short* __restrict__ val_ws) {
  __shared__ float offs[16][33];
  int lane = threadIdx.x;
  int r16 = lane & 15, kg = lane >> 4;
  int row0 = blockIdx.x * 16;

  f4_t acc[2] = {};
  const float* arow = x + (size_t)(row0 + r16) * KD;       // this lane's A row
  const unsigned short* bcol0 = wofft + r16 * KD;          // B col r16
  const unsigned short* bcol1 = wofft + (16 + r16) * KD;   // B col 16+r16

#pragma unroll 4
  for (int ks = 0; ks < 32; ++ks) {
    int k0 = ks * 32 + kg * 8;
    float4 v0 = *(const float4*)(arow + k0);
    float4 v1 = *(const float4*)(arow + k0 + 4);
    bf8_t a;
    a[0] = (short)f2bf(v0.x); a[1] = (short)f2bf(v0.y);
    a[2] = (short)f2bf(v0.z); a[3] = (short)f2bf(v0.w);
    a[4] = (short)f2bf(v1.x); a[5] = (short)f2bf(v1.y);
    a[6] = (short)f2bf(v1.z); a[7] = (short)f2bf(v1.w);
    bf8_t b0 = *(const bf8_t*)(bcol0 + k0);
    bf8_t b1 = *(const bf8_t*)(bcol1 + k0);
    acc[0] = __builtin_amdgcn_mfma_f32_16x16x32_bf16(a, b0, acc[0], 0, 0, 0);
    acc[1] = __builtin_amdgcn_mfma_f32_16x16x32_bf16(a, b1, acc[1], 0, 0, 0);
  }
  // C layout: col = lane&15, row = (lane>>4)*4 + reg
#pragma unroll
  for (int n = 0; n < 2; ++n)
#pragma unroll
    for (int r = 0; r < 4; ++r)
      offs[kg * 4 + r][n * 16 + r16] = acc[n][r] + b_off[n * 16 + r16];
  __syncthreads();

  // Phase 2: sampling. lane = channel c.
  for (int rp = 0; rp < 16; ++rp) {
    int rg = row0 + rp;
    int b = rg / NW, w = rg - b * NW;
    const float* xb = x + (size_t)b * (NL * NC);
    unsigned short* dst = val_ws + (size_t)rg * KD;
#pragma unroll 4
    for (int k = 0; k < 16; ++k) {
      float dy = offs[rp][2 * k], dx = offs[rp][2 * k + 1];
      float wy = fmaxf(0.f, 1.f - fabsf(dy));
      float px = (float)(w * 16 + k) + dx;
      float x0f = floorf(px);
      float frac = px - x0f;
      int x0 = (int)x0f;
      float v0 = (x0 >= 0 && x0 < NL) ? xb[x0 * 64 + lane] : 0.f;
      float v1 = (x0 + 1 >= 0 && x0 + 1 < NL) ? xb[(x0 + 1) * 64 + lane] : 0.f;
      float val = wy * ((1.f - frac) * v0 + frac * v1);
      dst[k * 64 + lane] = f2bf(val);
    }
  }
}

// ---------------------------------------------------------------------------
// main GEMM: out[b*199 + w + 1][d] = sum_kc val[row][kc]*wdeft[d][kc] + b_def[d] + pe[w+1][d]
// grid (99, 4); BM=BN=128, BK=64; 4 waves 2x2, each 64x64.
// global_load_lds staging, linear LDS + XOR chunk swizzle (chunk j <-> j^(r&7)).
// ---------------------------------------------------------------------------
__launch_bounds__(256)
__global__ void gemm_kernel(const unsigned short* __restrict__ val_ws,
                            const unsigned short* __restrict__ wdeft,
                            const float* __restrict__ b_def, const float* __restrict__ pe,
                            float* __restrict__ out) {
  __shared__ unsigned short As[128 * 64];
  __shared__ unsigned short Bs[128 * 64];
  int tid = threadIdx.x;
  int mt = blockIdx.x, nt = blockIdx.y;
  int lane = tid & 63, wid = tid >> 6;
  int r16 = lane & 15, kg = lane >> 4;
  int wr = wid >> 1, wc = wid & 1;
  f4_t acc[4][4] = {};

  // staging geometry: seg = wid*4+i owns 1KB (8 rows); lane l -> (row seg*8 + l>>3, chunk l&7)
  int r_st = lane >> 3;
  int j_st = lane & 7;
  const char* aBase = (const char*)val_ws + (size_t)mt * 128 * 2048;
  const char* bBase = (const char*)wdeft + (size_t)nt * 128 * 2048;

  for (int ks = 0; ks < 16; ++ks) {
    __syncthreads();   // all waves done reading previous tile
#pragma unroll
    for (int i = 0; i < 4; ++i) {
      int seg = wid * 4 + i;
      int r = seg * 8 + r_st;
      int src_off = ((j_st ^ (r & 7)) << 4);  // inverse-swizzled source chunk
      gl_lds16(aBase + (size_t)r * 2048 + ks * 128 + src_off, &As[seg * 512]);
      gl_lds16(bBase + (size_t)r * 2048 + ks * 128 + src_off, &Bs[seg * 512]);
    }
    __syncthreads();   // drains vmcnt(0) then barrier -> tile ready
#pragma unroll
    for (int jb = 0; jb < 8; jb += 4) {   // chunk-index base (0 -> k 0..31, 4 -> k 32..63)
      bf8_t af[4], bf[4];
#pragma unroll
      for (int m = 0; m < 4; ++m) {
        int R = wr * 64 + m * 16 + r16;
        af[m] = *(const bf8_t*)&As[R * 64 + (((jb + kg) ^ (R & 7)) << 3)];
      }
#pragma unroll
      for (int n = 0; n < 4; ++n) {
        int Rc = wc * 64 + n * 16 + r16;
        bf[n] = *(const bf8_t*)&Bs[Rc * 64 + (((jb + kg) ^ (Rc & 7)) << 3)];
      }
#pragma unroll
      for (int m = 0; m < 4; ++m)
#pragma unroll
        for (int n = 0; n < 4; ++n)
          acc[m][n] = __builtin_amdgcn_mfma_f32_16x16x32_bf16(af[m], bf[n], acc[m][n], 0, 0, 0);
    }
  }
#pragma unroll
  for (int m = 0; m < 4; ++m)
#pragma unroll
    for (int n = 0; n < 4; ++n)
#pragma unroll
      for (int r = 0; r < 4; ++r) {
        int grow = mt * 128 + wr * 64 + m * 16 + kg * 4 + r;
        int gcol = nt * 128 + wc * 64 + n * 16 + r16;
        int bi = grow / NW, wi = grow - bi * NW;
        out[((size_t)(bi * 199 + wi + 1)) * 512 + gcol] =
            acc[m][n][r] + b_def[gcol] + pe[(wi + 1) * 512 + gcol];
      }
}

extern "C" void kernel_launch(void* const* d_in, const int* in_sizes, int n_in,
                              void* d_out, int out_size, void* d_ws, size_t ws_size,
                              hipStream_t stream) {
  const float* x     = (const float*)d_in[0];
  const float* w_off = (const float*)d_in[1];
  const float* b_off = (const float*)d_in[2];
  const float* w_def = (const float*)d_in[3];
  const float* b_def = (const float*)d_in[4];
  const float* cls   = (const float*)d_in[5];
  float* out = (float*)d_out;
  char* ws = (char*)d_ws;
  // workspace layout (bytes):
  unsigned short* val_ws = (unsigned short*)ws;                  // 12672*1024*2 = 25,952,256
  unsigned short* wofft  = (unsigned short*)(ws + 25952256);     // 32*1024*2    = 65,536
  unsigned short* wdeft  = (unsigned short*)(ws + 26017792);     // 512*1024*2   = 1,048,576
  float* pe              = (float*)(ws + 27066368);              // 199*512*4    = 407,552 (end 27,473,920)

  prep_kernel<<<2702, 256, 0, stream>>>(w_off, w_def, cls, wofft, wdeft, pe, out);
  offsample_kernel<<<NM / 16, 64, 0, stream>>>(x, wofft, b_off, val_ws);
  gemm_kernel<<<dim3(99, 4), 256, 0, stream>>>(val_ws, wdeft, b_def, pe, out);
}

// Round 3
// 68.282 us; speedup vs baseline: 1.8596x; 1.8596x over previous
//
#include <hip/hip_runtime.h>
#include <math.h>
#include <stdint.h>

#define NB 64
#define NL 3168
#define NC 64
#define ND 512
#define NK 16
#define NW 198
#define NM 12672   // NB*NW rows
#define KD 1024    // NC*NK contraction dim, flattened as k*64+c

typedef __attribute__((ext_vector_type(8))) short bf8_t;   // 8 bf16 (4 VGPR) MFMA A/B frag
typedef __attribute__((ext_vector_type(4))) float f4_t;    // MFMA C/D frag

typedef const unsigned int __attribute__((address_space(1)))* as1_u32p;
typedef unsigned int __attribute__((address_space(3)))* as3_u32p;

__device__ __forceinline__ void gl_lds16(const void* g, void* l) {
  // global -> LDS direct DMA, 16B per lane. LDS dest = wave-uniform base + lane*16.
  __builtin_amdgcn_global_load_lds((as1_u32p)(uintptr_t)g,
                                   (as3_u32p)(unsigned int)(uintptr_t)l, 16, 0, 0);
}

__device__ __forceinline__ unsigned short f2bf(float f) {
  union { float f; unsigned u; } v; v.f = f;
  unsigned r = v.u + 0x7FFFu + ((v.u >> 16) & 1u);
  return (unsigned short)(r >> 16);
}

// ---------------------------------------------------------------------------
// prep: wdeft[d][k*64+c] = w_def[d][c][k] (bf16); wofft[o][k*64+c] = w_off[o][c][k];
//       pe[pos][d] table (f32); cls rows of output
// ---------------------------------------------------------------------------
__global__ void prep_kernel(const float* __restrict__ w_off, const float* __restrict__ w_def,
                            const float* __restrict__ cls, unsigned short* __restrict__ wofft,
                            unsigned short* __restrict__ wdeft, float* __restrict__ pe,
                            float* __restrict__ out) {
  int id = blockIdx.x * 256 + threadIdx.x;
  if (id < 524288) {
    int d = id >> 10, kc = id & 1023, k = kc >> 6, c = kc & 63;
    wdeft[id] = f2bf(w_def[d * 1024 + c * 16 + k]);
    return;
  }
  id -= 524288;
  if (id < 32768) {
    int o = id >> 10, kc = id & 1023, k = kc >> 6, c = kc & 63;
    wofft[id] = f2bf(w_off[o * 1024 + c * 16 + k]);
    return;
  }
  id -= 32768;
  if (id < 101888) {   // 199 * 512 positional-encoding table
    int pos = id >> 9, d = id & 511;
    int i = d >> 1;
    float freq = expf((float)(2 * i) * (-9.210340371976184f / 512.0f));
    float arg = (float)pos * freq;
    pe[id] = (d & 1) ? cosf(arg) : sinf(arg);
    return;
  }
  id -= 101888;
  {  // 64 * 512 cls-token rows: out[b][0][d] = cls[d] + pe[0][d]
    int b = id >> 9, d = id & 511;
    out[(size_t)(b * 199) * 512 + d] = cls[d] + ((d & 1) ? 1.0f : 0.0f);
  }
}

// ---------------------------------------------------------------------------
// off GEMM, split-K: 792 blocks x 256 thr (4 waves). Block = 16 rows, N=32, K=1024.
// Wave w handles K-slice [w*256, w*256+256): 8 MFMA K-steps, A direct-from-global
// f32->bf16, B from wofft (L2-resident). Partials reduced via LDS, + bias.
// ---------------------------------------------------------------------------
__launch_bounds__(256)
__global__ void offgemm_kernel(const float* __restrict__ x, const unsigned short* __restrict__ wofft,
                               const float* __restrict__ b_off, float* __restrict__ off_ws) {
  __shared__ float partial[4][16][33];
  int tid = threadIdx.x;
  int lane = tid & 63, wid = tid >> 6;
  int r16 = lane & 15, kg = lane >> 4;
  int row0 = blockIdx.x * 16;

  f4_t acc[2] = {};
  const float* arow = x + (size_t)(row0 + r16) * KD + wid * 256;   // this lane's A row, K-slice
  const unsigned short* bcol0 = wofft + r16 * KD + wid * 256;      // B col r16
  const unsigned short* bcol1 = wofft + (16 + r16) * KD + wid * 256;

#pragma unroll
  for (int ks = 0; ks < 8; ++ks) {
    int k0 = ks * 32 + kg * 8;
    float4 v0 = *(const float4*)(arow + k0);
    float4 v1 = *(const float4*)(arow + k0 + 4);
    bf8_t a;
    a[0] = (short)f2bf(v0.x); a[1] = (short)f2bf(v0.y);
    a[2] = (short)f2bf(v0.z); a[3] = (short)f2bf(v0.w);
    a[4] = (short)f2bf(v1.x); a[5] = (short)f2bf(v1.y);
    a[6] = (short)f2bf(v1.z); a[7] = (short)f2bf(v1.w);
    bf8_t b0 = *(const bf8_t*)(bcol0 + k0);
    bf8_t b1 = *(const bf8_t*)(bcol1 + k0);
    acc[0] = __builtin_amdgcn_mfma_f32_16x16x32_bf16(a, b0, acc[0], 0, 0, 0);
    acc[1] = __builtin_amdgcn_mfma_f32_16x16x32_bf16(a, b1, acc[1], 0, 0, 0);
  }
  // C layout: col = lane&15 (=B col within 16), row = kg*4 + reg (=A row within 16)
#pragma unroll
  for (int n = 0; n < 2; ++n)
#pragma unroll
    for (int r = 0; r < 4; ++r)
      partial[wid][kg * 4 + r][n * 16 + r16] = acc[n][r];
  __syncthreads();
  // reduce 4 partials; 256 threads x 2 outputs
#pragma unroll
  for (int i = 0; i < 2; ++i) {
    int idx = tid * 2 + i;
    int r = idx >> 5, o = idx & 31;
    float s = partial[0][r][o] + partial[1][r][o] + partial[2][r][o] + partial[3][r][o];
    off_ws[(row0 + r) * 32 + o] = s + b_off[o];
  }
}

// ---------------------------------------------------------------------------
// sampling: val_ws[row][k*64+c] = wy * ((1-frac)*v0 + frac*v1)  (bf16)
// one wave per row; lane = channel c
// ---------------------------------------------------------------------------
__global__ void sample_kernel(const float* __restrict__ x, const float* __restrict__ off_ws,
                              unsigned short* __restrict__ val_ws) {
  int tid = threadIdx.x;
  int wid = tid >> 6, lane = tid & 63;
  int row = blockIdx.x * 4 + wid;
  int b = row / NW, w = row - b * NW;
  const float* xb = x + (size_t)b * (NL * NC);
  const float* offr = off_ws + row * 32;
  unsigned short* dst = val_ws + (size_t)row * KD;
#pragma unroll
  for (int k = 0; k < 16; ++k) {
    float dy = offr[2 * k], dx = offr[2 * k + 1];
    float wy = fmaxf(0.f, 1.f - fabsf(dy));
    float px = (float)(w * 16 + k) + dx;
    float x0f = floorf(px);
    float frac = px - x0f;
    int x0 = (int)x0f;
    float v0 = (x0 >= 0 && x0 < NL) ? xb[x0 * 64 + lane] : 0.f;
    float v1 = (x0 + 1 >= 0 && x0 + 1 < NL) ? xb[(x0 + 1) * 64 + lane] : 0.f;
    float val = wy * ((1.f - frac) * v0 + frac * v1);
    dst[k * 64 + lane] = f2bf(val);
  }
}

// ---------------------------------------------------------------------------
// main GEMM: out[b*199 + w + 1][d] = sum_kc val[row][kc]*wdeft[d][kc] + b_def[d] + pe[w+1][d]
// grid (99, 4); BM=BN=128, BK=64; 4 waves 2x2, each 64x64.
// global_load_lds staging, linear LDS + XOR chunk swizzle (chunk j <-> j^(r&7)).
// ---------------------------------------------------------------------------
__launch_bounds__(256)
__global__ void gemm_kernel(const unsigned short* __restrict__ val_ws,
                            const unsigned short* __restrict__ wdeft,
                            const float* __restrict__ b_def, const float* __restrict__ pe,
                            float* __restrict__ out) {
  __shared__ unsigned short As[128 * 64];
  __shared__ unsigned short Bs[128 * 64];
  int tid = threadIdx.x;
  int mt = blockIdx.x, nt = blockIdx.y;
  int lane = tid & 63, wid = tid >> 6;
  int r16 = lane & 15, kg = lane >> 4;
  int wr = wid >> 1, wc = wid & 1;
  f4_t acc[4][4] = {};

  // staging geometry: seg = wid*4+i owns 1KB (8 rows); lane l -> (row seg*8 + l>>3, chunk l&7)
  int r_st = lane >> 3;
  int j_st = lane & 7;
  const char* aBase = (const char*)val_ws + (size_t)mt * 128 * 2048;
  const char* bBase = (const char*)wdeft + (size_t)nt * 128 * 2048;

  for (int ks = 0; ks < 16; ++ks) {
    __syncthreads();   // all waves done reading previous tile
#pragma unroll
    for (int i = 0; i < 4; ++i) {
      int seg = wid * 4 + i;
      int r = seg * 8 + r_st;
      int src_off = ((j_st ^ (r & 7)) << 4);  // inverse-swizzled source chunk
      gl_lds16(aBase + (size_t)r * 2048 + ks * 128 + src_off, &As[seg * 512]);
      gl_lds16(bBase + (size_t)r * 2048 + ks * 128 + src_off, &Bs[seg * 512]);
    }
    __syncthreads();   // drains vmcnt(0) then barrier -> tile ready
#pragma unroll
    for (int jb = 0; jb < 8; jb += 4) {   // chunk-index base (0 -> k 0..31, 4 -> k 32..63)
      bf8_t af[4], bf[4];
#pragma unroll
      for (int m = 0; m < 4; ++m) {
        int R = wr * 64 + m * 16 + r16;
        af[m] = *(const bf8_t*)&As[R * 64 + (((jb + kg) ^ (R & 7)) << 3)];
      }
#pragma unroll
      for (int n = 0; n < 4; ++n) {
        int Rc = wc * 64 + n * 16 + r16;
        bf[n] = *(const bf8_t*)&Bs[Rc * 64 + (((jb + kg) ^ (Rc & 7)) << 3)];
      }
#pragma unroll
      for (int m = 0; m < 4; ++m)
#pragma unroll
        for (int n = 0; n < 4; ++n)
          acc[m][n] = __builtin_amdgcn_mfma_f32_16x16x32_bf16(af[m], bf[n], acc[m][n], 0, 0, 0);
    }
  }
#pragma unroll
  for (int m = 0; m < 4; ++m)
#pragma unroll
    for (int n = 0; n < 4; ++n)
#pragma unroll
      for (int r = 0; r < 4; ++r) {
        int grow = mt * 128 + wr * 64 + m * 16 + kg * 4 + r;
        int gcol = nt * 128 + wc * 64 + n * 16 + r16;
        int bi = grow / NW, wi = grow - bi * NW;
        out[((size_t)(bi * 199 + wi + 1)) * 512 + gcol] =
            acc[m][n][r] + b_def[gcol] + pe[(wi + 1) * 512 + gcol];
      }
}

extern "C" void kernel_launch(void* const* d_in, const int* in_sizes, int n_in,
                              void* d_out, int out_size, void* d_ws, size_t ws_size,
                              hipStream_t stream) {
  const float* x     = (const float*)d_in[0];
  const float* w_off = (const float*)d_in[1];
  const float* b_off = (const float*)d_in[2];
  const float* w_def = (const float*)d_in[3];
  const float* b_def = (const float*)d_in[4];
  const float* cls   = (const float*)d_in[5];
  float* out = (float*)d_out;
  char* ws = (char*)d_ws;
  // workspace layout (bytes):
  unsigned short* val_ws = (unsigned short*)ws;                  // 12672*1024*2 = 25,952,256
  unsigned short* wofft  = (unsigned short*)(ws + 25952256);     // 32*1024*2    = 65,536
  unsigned short* wdeft  = (unsigned short*)(ws + 26017792);     // 512*1024*2   = 1,048,576
  float* pe              = (float*)(ws + 27066368);              // 199*512*4    = 407,552
  float* off_ws          = (float*)(ws + 27473920);              // 12672*32*4   = 1,622,016 (end 29,095,936)

  prep_kernel<<<2702, 256, 0, stream>>>(w_off, w_def, cls, wofft, wdeft, pe, out);
  offgemm_kernel<<<NM / 16, 256, 0, stream>>>(x, wofft, b_off, off_ws);
  sample_kernel<<<NM / 4, 256, 0, stream>>>(x, off_ws, val_ws);
  gemm_kernel<<<dim3(99, 4), 256, 0, stream>>>(val_ws, wdeft, b_def, pe, out);
}